// Round 1
// baseline (1495.941 us; speedup 1.0000x reference)
//
#include <hip/hip_runtime.h>

// C3 partial conv: x[64,6,256,256] f32, W[16,6,5,5] f32 (sparse connection table
// handled by iterating connected channels only), b[16]. out[64,16,252,252] f32.
// out = 1.7159 * tanh((2/3) * (conv_valid(x, W) + b))
//
// Round 4: occupancy attack. Round-3 kernel was latency-bound: VGPR=172 ->
// 2 waves/SIMD (Occupancy 11.8%), VALUBusy 37%, both HBM (7%) and FMA (14%)
// pipes idle. Split the 16 output channels into 2 groups of 8 so the live
// accumulator file halves (acc[16][2]=32 -> acc[8][2]=16 VGPRs), re-reading
// the LDS windows per group (LDS issue is cheap: ~14us extra). Cap registers
// at 128 via __launch_bounds__(256,4) -> 4 waves/SIMD. sched_barrier between
// groups keeps the two groups' live ranges from overlapping.

__global__ __launch_bounds__(256, 4) void c3_partial_conv_kernel(
    const float* __restrict__ x,   // [64,6,256,256]
    const float* __restrict__ W,   // [16,6,5,5]
    const float* __restrict__ b,   // [16]
    float* __restrict__ out)       // [64,16,252,252]
{
    // Reverse maps per group: for input channel c, the output channels in
    // this group that consume it (padded; count arrays give real lengths).
    constexpr int G0N[6] = {4, 5, 5, 5, 4, 3};
    constexpr int G0O[6][5] = {
        {0, 4, 5, 6, 0},
        {0, 1, 5, 6, 7},
        {0, 1, 2, 6, 7},
        {1, 2, 3, 6, 7},
        {2, 3, 4, 7, 0},
        {3, 4, 5, 0, 0}};
    constexpr int G1N[6] = {6, 5, 5, 5, 6, 7};
    constexpr int G1O[6][7] = {
        {9, 10, 11, 12, 14, 15, 8},
        {10, 11, 12, 13, 15, 8, 8},
        {8, 11, 13, 14, 15, 8, 8},
        {8, 9, 12, 14, 15, 8, 8},
        {8, 9, 10, 12, 13, 15, 8},
        {8, 9, 10, 11, 13, 14, 15}};

    // Input tile: 6 ch x 20 rows x 36 cols (row stride 40 floats, 16B-aligned).
    __shared__ float lds[6][20][40];  // 19200 B

    const int tx  = threadIdx.x;   // 0..31 -> output col within tile
    const int ty  = threadIdx.y;   // 0..7  -> output row pair
    const int tid = ty * 32 + tx;

    const int tileX = blockIdx.x << 5;   // 0..224
    const int tileY = blockIdx.y << 4;   // 0..240
    const int batch = blockIdx.z;

    const float* xb = x + (size_t)batch * 6 * 256 * 256;

    // ---- stage input tile: float4 chunks. 6*20*9 = 1080 chunks ----
    for (int i = tid; i < 1080; i += 256) {
        int c   = i / 180;
        int rem = i - c * 180;
        int r   = rem / 9;
        int q   = rem - r * 9;
        int gr  = tileY + r;
        int gc0 = tileX + (q << 2);
        float4 v = make_float4(0.f, 0.f, 0.f, 0.f);
        if (gr < 256 && gc0 < 256)    // chunk fully in-bounds or fully out
            v = *reinterpret_cast<const float4*>(&xb[(c * 256 + gr) * 256 + gc0]);
        *reinterpret_cast<float4*>(&lds[c][r][q << 2]) = v;
    }
    __syncthreads();

    const int row0 = ty << 1;            // local output row base (0..14)
    const int ocol = tileX + tx;
    float* ob = out + (size_t)batch * 16 * 252 * 252;
    const bool colok = (ocol < 252);

    // ================= group 0 : out channels 0..7 =================
    {
        float acc[8][2];
        #pragma unroll
        for (int o = 0; o < 8; ++o) {
            float bv = b[o];
            acc[o][0] = bv; acc[o][1] = bv;
        }

        #pragma unroll
        for (int c = 0; c < 6; ++c) {
            float win[6][5];
            #pragma unroll
            for (int r = 0; r < 6; ++r)
                #pragma unroll
                for (int j = 0; j < 5; ++j)
                    win[r][j] = lds[c][row0 + r][tx + j];

            #pragma unroll
            for (int oi = 0; oi < G0N[c]; ++oi) {
                const int o = G0O[c][oi];
                const float* wp = W + (o * 6 + c) * 25;
                #pragma unroll
                for (int ky = 0; ky < 5; ++ky)
                    #pragma unroll
                    for (int kx = 0; kx < 5; ++kx) {
                        const float wv = wp[ky * 5 + kx];   // uniform -> s_load
                        acc[o][0] = fmaf(win[ky + 0][kx], wv, acc[o][0]);
                        acc[o][1] = fmaf(win[ky + 1][kx], wv, acc[o][1]);
                    }
            }
        }

        if (colok) {
            #pragma unroll
            for (int o = 0; o < 8; ++o)
                #pragma unroll
                for (int dy = 0; dy < 2; ++dy) {
                    int orow = tileY + row0 + dy;
                    if (orow < 252) {
                        float z = acc[o][dy] * (2.0f / 3.0f);
                        float e = __expf(2.0f * z);              // v_exp_f32 path
                        float rr = __builtin_amdgcn_rcpf(e + 1.0f);
                        ob[(o * 252 + orow) * 252 + ocol] = 1.7159f * (1.0f - 2.0f * rr);
                    }
                }
        }
    }

    // keep the two groups' live ranges separate (don't let the scheduler
    // hoist group-1 window loads above group-0 epilogue)
    __builtin_amdgcn_sched_barrier(0);

    // ================= group 1 : out channels 8..15 =================
    {
        float acc[8][2];
        #pragma unroll
        for (int o = 0; o < 8; ++o) {
            float bv = b[8 + o];
            acc[o][0] = bv; acc[o][1] = bv;
        }

        #pragma unroll
        for (int c = 0; c < 6; ++c) {
            float win[6][5];
            #pragma unroll
            for (int r = 0; r < 6; ++r)
                #pragma unroll
                for (int j = 0; j < 5; ++j)
                    win[r][j] = lds[c][row0 + r][tx + j];

            #pragma unroll
            for (int oi = 0; oi < G1N[c]; ++oi) {
                const int o = G1O[c][oi];            // 8..15, compile-time
                const float* wp = W + (o * 6 + c) * 25;
                #pragma unroll
                for (int ky = 0; ky < 5; ++ky)
                    #pragma unroll
                    for (int kx = 0; kx < 5; ++kx) {
                        const float wv = wp[ky * 5 + kx];
                        acc[o - 8][0] = fmaf(win[ky + 0][kx], wv, acc[o - 8][0]);
                        acc[o - 8][1] = fmaf(win[ky + 1][kx], wv, acc[o - 8][1]);
                    }
            }
        }

        if (colok) {
            #pragma unroll
            for (int o = 0; o < 8; ++o)
                #pragma unroll
                for (int dy = 0; dy < 2; ++dy) {
                    int orow = tileY + row0 + dy;
                    if (orow < 252) {
                        float z = acc[o][dy] * (2.0f / 3.0f);
                        float e = __expf(2.0f * z);
                        float rr = __builtin_amdgcn_rcpf(e + 1.0f);
                        ob[((8 + o) * 252 + orow) * 252 + ocol] = 1.7159f * (1.0f - 2.0f * rr);
                    }
                }
        }
    }
}

extern "C" void kernel_launch(void* const* d_in, const int* in_sizes, int n_in,
                              void* d_out, int out_size, void* d_ws, size_t ws_size,
                              hipStream_t stream) {
    const float* x = (const float*)d_in[0];
    const float* W = (const float*)d_in[1];
    const float* b = (const float*)d_in[2];
    float* out = (float*)d_out;

    dim3 grid(8, 16, 64);   // 8 col-tiles x 16 row-tiles x 64 batches
    dim3 block(32, 8);
    hipLaunchKernelGGL(c3_partial_conv_kernel, grid, block, 0, stream, x, W, b, out);
}

// Round 2
// 468.013 us; speedup vs baseline: 3.1964x; 3.1964x over previous
//
#include <hip/hip_runtime.h>

// C3 partial conv: x[64,6,256,256] f32, W[16,6,5,5] f32 (sparse connection table
// handled by iterating connected channels only), b[16]. out[64,16,252,252] f32.
// out = 1.7159 * tanh((2/3) * (conv_valid(x, W) + b))
//
// Round 5: de-confound round 4. The channel split (16 -> 2 groups of 8,
// halving live acc regs) is kept; the __launch_bounds__ min-waves arg is
// REMOVED -- it is a hard VGPR clamp to 64 on this compiler (rounds 2 and 4
// both: 3+ GB scratch spill traffic, 2.7x slower). Goal: natural VGPR
// allocation lands under the 168-reg 3-waves/SIMD boundary (round 3 was 172
// -> 2 waves/SIMD, latency-bound at VALUBusy 37%).

__global__ __launch_bounds__(256) void c3_partial_conv_kernel(
    const float* __restrict__ x,   // [64,6,256,256]
    const float* __restrict__ W,   // [16,6,5,5]
    const float* __restrict__ b,   // [16]
    float* __restrict__ out)       // [64,16,252,252]
{
    // Reverse maps per group: for input channel c, the output channels in
    // this group that consume it (count arrays give real lengths).
    constexpr int G0N[6] = {4, 5, 5, 5, 4, 3};
    constexpr int G0O[6][5] = {
        {0, 4, 5, 6, 0},
        {0, 1, 5, 6, 7},
        {0, 1, 2, 6, 7},
        {1, 2, 3, 6, 7},
        {2, 3, 4, 7, 0},
        {3, 4, 5, 0, 0}};
    constexpr int G1N[6] = {6, 5, 5, 5, 6, 7};
    constexpr int G1O[6][7] = {
        {9, 10, 11, 12, 14, 15, 8},
        {10, 11, 12, 13, 15, 8, 8},
        {8, 11, 13, 14, 15, 8, 8},
        {8, 9, 12, 14, 15, 8, 8},
        {8, 9, 10, 12, 13, 15, 8},
        {8, 9, 10, 11, 13, 14, 15}};

    // Input tile: 6 ch x 20 rows x 36 cols (row stride 40 floats, 16B-aligned).
    __shared__ float lds[6][20][40];  // 19200 B

    const int tx  = threadIdx.x;   // 0..31 -> output col within tile
    const int ty  = threadIdx.y;   // 0..7  -> output row pair
    const int tid = ty * 32 + tx;

    const int tileX = blockIdx.x << 5;   // 0..224
    const int tileY = blockIdx.y << 4;   // 0..240
    const int batch = blockIdx.z;

    const float* xb = x + (size_t)batch * 6 * 256 * 256;

    // ---- stage input tile: float4 chunks. 6*20*9 = 1080 chunks ----
    for (int i = tid; i < 1080; i += 256) {
        int c   = i / 180;
        int rem = i - c * 180;
        int r   = rem / 9;
        int q   = rem - r * 9;
        int gr  = tileY + r;
        int gc0 = tileX + (q << 2);
        float4 v = make_float4(0.f, 0.f, 0.f, 0.f);
        if (gr < 256 && gc0 < 256)    // chunk fully in-bounds or fully out
            v = *reinterpret_cast<const float4*>(&xb[(c * 256 + gr) * 256 + gc0]);
        *reinterpret_cast<float4*>(&lds[c][r][q << 2]) = v;
    }
    __syncthreads();

    const int row0 = ty << 1;            // local output row base (0..14)
    const int ocol = tileX + tx;
    float* ob = out + (size_t)batch * 16 * 252 * 252;
    const bool colok = (ocol < 252);

    // ================= group 0 : out channels 0..7 =================
    {
        float acc[8][2];
        #pragma unroll
        for (int o = 0; o < 8; ++o) {
            float bv = b[o];
            acc[o][0] = bv; acc[o][1] = bv;
        }

        #pragma unroll
        for (int c = 0; c < 6; ++c) {
            float win[6][5];
            #pragma unroll
            for (int r = 0; r < 6; ++r)
                #pragma unroll
                for (int j = 0; j < 5; ++j)
                    win[r][j] = lds[c][row0 + r][tx + j];

            #pragma unroll
            for (int oi = 0; oi < G0N[c]; ++oi) {
                const int o = G0O[c][oi];
                const float* wp = W + (o * 6 + c) * 25;
                #pragma unroll
                for (int ky = 0; ky < 5; ++ky)
                    #pragma unroll
                    for (int kx = 0; kx < 5; ++kx) {
                        const float wv = wp[ky * 5 + kx];   // uniform -> s_load
                        acc[o][0] = fmaf(win[ky + 0][kx], wv, acc[o][0]);
                        acc[o][1] = fmaf(win[ky + 1][kx], wv, acc[o][1]);
                    }
            }
        }

        if (colok) {
            #pragma unroll
            for (int o = 0; o < 8; ++o)
                #pragma unroll
                for (int dy = 0; dy < 2; ++dy) {
                    int orow = tileY + row0 + dy;
                    if (orow < 252) {
                        float z = acc[o][dy] * (2.0f / 3.0f);
                        float e = __expf(2.0f * z);              // v_exp_f32 path
                        float rr = __builtin_amdgcn_rcpf(e + 1.0f);
                        ob[(o * 252 + orow) * 252 + ocol] = 1.7159f * (1.0f - 2.0f * rr);
                    }
                }
        }
    }

    // keep the two groups' live ranges separate (don't let the scheduler
    // hoist group-1 window loads above group-0 epilogue)
    __builtin_amdgcn_sched_barrier(0);

    // ================= group 1 : out channels 8..15 =================
    {
        float acc[8][2];
        #pragma unroll
        for (int o = 0; o < 8; ++o) {
            float bv = b[8 + o];
            acc[o][0] = bv; acc[o][1] = bv;
        }

        #pragma unroll
        for (int c = 0; c < 6; ++c) {
            float win[6][5];
            #pragma unroll
            for (int r = 0; r < 6; ++r)
                #pragma unroll
                for (int j = 0; j < 5; ++j)
                    win[r][j] = lds[c][row0 + r][tx + j];

            #pragma unroll
            for (int oi = 0; oi < G1N[c]; ++oi) {
                const int o = G1O[c][oi];            // 8..15, compile-time
                const float* wp = W + (o * 6 + c) * 25;
                #pragma unroll
                for (int ky = 0; ky < 5; ++ky)
                    #pragma unroll
                    for (int kx = 0; kx < 5; ++kx) {
                        const float wv = wp[ky * 5 + kx];
                        acc[o - 8][0] = fmaf(win[ky + 0][kx], wv, acc[o - 8][0]);
                        acc[o - 8][1] = fmaf(win[ky + 1][kx], wv, acc[o - 8][1]);
                    }
            }
        }

        if (colok) {
            #pragma unroll
            for (int o = 0; o < 8; ++o)
                #pragma unroll
                for (int dy = 0; dy < 2; ++dy) {
                    int orow = tileY + row0 + dy;
                    if (orow < 252) {
                        float z = acc[o][dy] * (2.0f / 3.0f);
                        float e = __expf(2.0f * z);
                        float rr = __builtin_amdgcn_rcpf(e + 1.0f);
                        ob[((8 + o) * 252 + orow) * 252 + ocol] = 1.7159f * (1.0f - 2.0f * rr);
                    }
                }
        }
    }
}

extern "C" void kernel_launch(void* const* d_in, const int* in_sizes, int n_in,
                              void* d_out, int out_size, void* d_ws, size_t ws_size,
                              hipStream_t stream) {
    const float* x = (const float*)d_in[0];
    const float* W = (const float*)d_in[1];
    const float* b = (const float*)d_in[2];
    float* out = (float*)d_out;

    dim3 grid(8, 16, 64);   // 8 col-tiles x 16 row-tiles x 64 batches
    dim3 block(32, 8);
    hipLaunchKernelGGL(c3_partial_conv_kernel, grid, block, 0, stream, x, W, b, out);
}